// Round 1
// baseline (675.496 us; speedup 1.0000x reference)
//
#include <hip/hip_runtime.h>

// CorrelationLayer1D: out[b,d,h,w] = sum_c x1[b,c,h,w] * x2[b,c,h,w+d-80]
// B=8 C=128 H=160 W=320 D=81 (pad=80, stride 1)
//
// Block = one (b, h, w-tile of 64). 320 threads = 16 wi * 20 di.
// Thread computes a 4w x 4d register tile; di==0 additionally computes d=80.
// X1 [Kc][64] and X2 [Kc][144] staged in LDS per 32-channel chunk.

#define CB 8
#define CC 128
#define CH 160
#define CW 320
#define CD 81
#define CPAD 80
#define TW 64
#define KC 32
#define NTHR 320
#define X2W (TW + CPAD)   // 144
#define WTILES (CW / TW)  // 5

__global__ __launch_bounds__(NTHR, 4) void corr1d_kernel(
    const float* __restrict__ x1,
    const float* __restrict__ x2,
    float* __restrict__ out)
{
    __shared__ float ldsA[KC][TW];    //  8 KB
    __shared__ float ldsB[KC][X2W];   // 18 KB

    const int tid = threadIdx.x;
    const int bid = blockIdx.x;
    const int wt = bid % WTILES;
    const int h  = (bid / WTILES) % CH;
    const int b  = bid / (WTILES * CH);
    const int w0 = wt * TW;

    const int wi = tid & 15;     // [0,16)  -> 4 w's each
    const int di = tid >> 4;     // [0,20)  -> 4 d's each
    const int wl = wi * 4;       // local w base
    const int d0 = di * 4;       // d base

    float acc[4][4];
    float acc80[4];
    #pragma unroll
    for (int k = 0; k < 4; k++) {
        acc80[k] = 0.f;
        #pragma unroll
        for (int j = 0; j < 4; j++) acc[k][j] = 0.f;
    }

    const int hw = CH * CW;                       // 51200
    const float* x1p = x1 + ((b * CC) * CH + h) * CW + w0;  // + c*hw + j*4
    const float* x2p = x2 + ((b * CC) * CH + h) * CW;       // + c*hw + gw

    for (int c0 = 0; c0 < CC; c0 += KC) {
        // ---- stage X1: KC*TW/4 = 512 float4 ----
        for (int i = tid; i < (KC * TW / 4); i += NTHR) {
            int c = i >> 4;          // TW/4 = 16 float4 per row
            int j = i & 15;
            float4 v = *(const float4*)(x1p + (c0 + c) * hw + j * 4);
            *(float4*)&ldsA[c][j * 4] = v;
        }
        // ---- stage X2: KC*X2W/4 = 1152 float4 (zero-fill left OOB) ----
        for (int i = tid; i < (KC * X2W / 4); i += NTHR) {
            int c = i / 36;          // X2W/4 = 36 float4 per row
            int j = i - c * 36;
            int gw = w0 - CPAD + j * 4;   // multiple of 4, fully in or out
            float4 v = make_float4(0.f, 0.f, 0.f, 0.f);
            if (gw >= 0)
                v = *(const float4*)(x2p + (c0 + c) * hw + gw);
            *(float4*)&ldsB[c][j * 4] = v;
        }
        __syncthreads();

        #pragma unroll 4
        for (int c = 0; c < KC; c++) {
            float4 a  = *(const float4*)&ldsA[c][wl];
            float4 s0 = *(const float4*)&ldsB[c][wl + d0];
            float4 s1 = *(const float4*)&ldsB[c][wl + d0 + 4];
            const float av[4] = {a.x, a.y, a.z, a.w};
            const float s[8]  = {s0.x, s0.y, s0.z, s0.w,
                                 s1.x, s1.y, s1.z, s1.w};
            #pragma unroll
            for (int k = 0; k < 4; k++)
                #pragma unroll
                for (int j = 0; j < 4; j++)
                    acc[k][j] += av[j] * s[k + j];   // d = d0+k, w = wl+j

            if (di == 0) {
                float4 s80 = *(const float4*)&ldsB[c][wl + CPAD];
                const float sv[4] = {s80.x, s80.y, s80.z, s80.w};
                #pragma unroll
                for (int j = 0; j < 4; j++) acc80[j] += av[j] * sv[j];
            }
        }
        __syncthreads();
    }

    // ---- store: out[((b*D + d)*H + h)*W + w0 + wl] ----
    float* op = out + ((b * CD) * CH + h) * CW + w0 + wl;
    #pragma unroll
    for (int k = 0; k < 4; k++) {
        int d = d0 + k;
        float4 v = make_float4(acc[k][0], acc[k][1], acc[k][2], acc[k][3]);
        *(float4*)(op + d * hw) = v;
    }
    if (di == 0) {
        float4 v = make_float4(acc80[0], acc80[1], acc80[2], acc80[3]);
        *(float4*)(op + CPAD * hw) = v;
    }
}

extern "C" void kernel_launch(void* const* d_in, const int* in_sizes, int n_in,
                              void* d_out, int out_size, void* d_ws, size_t ws_size,
                              hipStream_t stream) {
    const float* x1 = (const float*)d_in[0];
    const float* x2 = (const float*)d_in[1];
    float* out = (float*)d_out;
    dim3 grid(CB * CH * WTILES);   // 6400
    dim3 block(NTHR);
    corr1d_kernel<<<grid, block, 0, stream>>>(x1, x2, out);
}

// Round 2
// 510.011 us; speedup vs baseline: 1.3245x; 1.3245x over previous
//
#include <hip/hip_runtime.h>

// CorrelationLayer1D via bf16 MFMA band-matmul.
// out[b,d,h,w] = sum_c x1[b,c,h,w] * x2[b,c,h,w+d-80]
// B=8 C=128 H=160 W=320 D=81.
//
// Block = (b, h, w-half of 160). 640 threads = 10 waves; wave s owns w-subtile
// [w0+16s, w0+16s+16). Per subtile: 6 N-tiles of 16 x2-columns covering the
// 96-col band; D[m][n] diagonals d = 16t + n - m in [0,80] are the outputs.
// x1 (160 rows) and x2 (240 rows, 80-col halo) staged transposed to bf16
// LDS [w][c], row stride 72 bf16 (even bank spread), K staged in 2 chunks of 64.

#define CB 8
#define CC 128
#define CH 160
#define CW 320
#define CD 81
#define CPAD 80
#define TW 160
#define NTHR 640
#define AROWS 160
#define BROWS 240
#define KC 64
#define ROWP 72      // LDS row stride in bf16 elements (144 B)
#define HW (CH*CW)   // 51200

typedef __attribute__((ext_vector_type(8))) short short8;
typedef __attribute__((ext_vector_type(4))) float f32x4;

__device__ __forceinline__ unsigned pk2(float a, float b) {
    // round-to-nearest-even fp32 -> bf16, packed pair
    unsigned ua = __float_as_uint(a), ub = __float_as_uint(b);
    ua = (ua + 0x7fffu + ((ua >> 16) & 1u)) >> 16;
    ub = (ub + 0x7fffu + ((ub >> 16) & 1u)) >> 16;
    return ua | (ub << 16);
}

__global__ __launch_bounds__(NTHR, 5) void corr1d_mfma(
    const float* __restrict__ x1,
    const float* __restrict__ x2,
    float* __restrict__ out)
{
    __shared__ __align__(16) unsigned short lA[AROWS * ROWP];  // 23.0 KB
    __shared__ __align__(16) unsigned short lB[BROWS * ROWP];  // 34.6 KB

    const int tid = threadIdx.x;
    const int bid = blockIdx.x;
    const int wt = bid & 1;
    const int h  = (bid >> 1) % CH;
    const int b  = bid / (2 * CH);
    const int w0 = wt * TW;

    const int lane = tid & 63;
    const int s    = tid >> 6;   // subtile 0..9
    const int n    = lane & 15;
    const int q    = lane >> 4;

    const float* x1p = x1 + ((size_t)b * CC * CH + (size_t)h) * CW;
    const float* x2p = x2 + ((size_t)b * CC * CH + (size_t)h) * CW;

    f32x4 acc[6];
#pragma unroll
    for (int t = 0; t < 6; t++) acc[t] = (f32x4){0.f, 0.f, 0.f, 0.f};

    for (int c0 = 0; c0 < CC; c0 += KC) {
        if (c0) __syncthreads();

        // ---- stage: 100 w-row-quads x 16 c-quads = 1600 tiles of 4w x 4c ----
#pragma unroll
        for (int j = 0; j < 3; j++) {
            int i = tid + j * NTHR;
            if (i < 1600) {
                int cq = i & 15;
                int rt = i >> 4;        // 0..39 -> A, 40..99 -> B
                int kl = cq << 2;       // k_local 0..60
                int c  = c0 + kl;
                float4 v[4];
                unsigned short* dst;
                if (rt < 40) {
                    int gw = w0 + (rt << 2);
                    const float* p = x1p + (size_t)c * HW + gw;
#pragma unroll
                    for (int cc = 0; cc < 4; cc++)
                        v[cc] = *(const float4*)(p + (size_t)cc * HW);
                    dst = &lA[(rt << 2) * ROWP + kl];
                } else {
                    int rb = rt - 40;
                    int gw = w0 - CPAD + (rb << 2);
                    if (gw >= 0) {
                        const float* p = x2p + (size_t)c * HW + gw;
#pragma unroll
                        for (int cc = 0; cc < 4; cc++)
                            v[cc] = *(const float4*)(p + (size_t)cc * HW);
                    } else {
#pragma unroll
                        for (int cc = 0; cc < 4; cc++)
                            v[cc] = make_float4(0.f, 0.f, 0.f, 0.f);
                    }
                    dst = &lB[(rb << 2) * ROWP + kl];
                }
                // 4x4 register transpose, bf16-pack, 4 x ds_write_b64
                uint2 r0 = make_uint2(pk2(v[0].x, v[1].x), pk2(v[2].x, v[3].x));
                uint2 r1 = make_uint2(pk2(v[0].y, v[1].y), pk2(v[2].y, v[3].y));
                uint2 r2 = make_uint2(pk2(v[0].z, v[1].z), pk2(v[2].z, v[3].z));
                uint2 r3 = make_uint2(pk2(v[0].w, v[1].w), pk2(v[2].w, v[3].w));
                *(uint2*)(dst + 0 * ROWP) = r0;
                *(uint2*)(dst + 1 * ROWP) = r1;
                *(uint2*)(dst + 2 * ROWP) = r2;
                *(uint2*)(dst + 3 * ROWP) = r3;
            }
        }
        __syncthreads();

        // ---- compute: wave s, 6 N-tiles, K chunk of 64 = 2 MFMA-K steps ----
        const unsigned short* arow = &lA[(16 * s + n) * ROWP];
#pragma unroll
        for (int ko = 0; ko < KC; ko += 32) {
            short8 av = *(const short8*)(arow + ko + 8 * q);
#pragma unroll
            for (int t = 0; t < 6; t++) {
                short8 bv = *(const short8*)(&lB[(16 * (s + t) + n) * ROWP + ko + 8 * q]);
                acc[t] = __builtin_amdgcn_mfma_f32_16x16x32_bf16(av, bv, acc[t], 0, 0, 0);
            }
        }
    }

    // ---- epilogue: scatter valid diagonals d = 16t + n - m ----
    float* op = out + ((size_t)b * CD * CH + (size_t)h) * CW + w0 + 16 * s;
#pragma unroll
    for (int t = 0; t < 6; t++) {
#pragma unroll
        for (int r = 0; r < 4; r++) {
            int m = 4 * q + r;
            int d = 16 * t + n - m;
            if (d >= 0 && d <= CPAD)
                op[(size_t)d * HW + m] = acc[t][r];
        }
    }
}

extern "C" void kernel_launch(void* const* d_in, const int* in_sizes, int n_in,
                              void* d_out, int out_size, void* d_ws, size_t ws_size,
                              hipStream_t stream) {
    const float* x1 = (const float*)d_in[0];
    const float* x2 = (const float*)d_in[1];
    float* out = (float*)d_out;
    dim3 grid(CB * CH * 2);   // 2560
    dim3 block(NTHR);
    corr1d_mfma<<<grid, block, 0, stream>>>(x1, x2, out);
}